// Round 15
// baseline (4300.331 us; speedup 1.0000x reference)
//
#include <hip/hip_runtime.h>
#include <math.h>

#define N_PTS 16384
#define N_CLUSTERS 4096
#define KNN_K 16
#define C_IN 64
#define C_OUT 128
#define FAN_IN 67
#define N_ROWS (N_CLUSTERS * KNN_K)   // 65536
#define NBINS 256

typedef float vf2 __attribute__((ext_vector_type(2)));
typedef unsigned long long u64;

// ---------------------------------------------------------------------------
// init: pp[i] = |pos_i|^2 (reference op order, no FMA), zero colsum/colsumsq
// ---------------------------------------------------------------------------
__global__ void init_kernel(const float* __restrict__ pos, float* __restrict__ pp,
                            float* __restrict__ cz) {
#pragma clang fp contract(off)
    int i = blockIdx.x * 256 + threadIdx.x;
    if (i < N_PTS) {
        float a = pos[i * 3 + 0], b = pos[i * 3 + 1], c = pos[i * 3 + 2];
        pp[i] = ((a * a) + (b * b)) + (c * c);
    }
    if (blockIdx.x == 0 && threadIdx.x < 256) cz[threadIdx.x] = 0.0f;
}

// ---------------------------------------------------------------------------
// FPS v18 = v17 (fps 3625us) + INTERLEAVED SLAB-SHARING.
// v17 post-mortem: VALU budget shows ~8.3 of 16 half-slab waves active/step
// (half-width slabs doubled boundary crossings vs v10's ~2.5) -> per-SIMD
// active update issue ~960cyc dominates.  Fix: wave pairs share a v10-WIDTH
// slab via slot interleave -- slab s = slots [2048s,+2048), wave 2s takes
// even slots, wave 2s+1 odd slots.  Both waves span ~the slab's x-interval,
// so their (still per-wave-exact) skip tests activate together: active
// waves ~ 2 x 2.5 = 5, and the pair lands on different SIMDs (w%4) ->
// per-SIMD update issue ~600cyc.  ONLY the gather slot mapping changes;
// intervals/skip/key/reduce machinery is v17 verbatim; orig-idx tie-break
// makes placement irrelevant -> bit-exact winner sequence.
// Machinery recap (proven v10/v16/v17):
//   - x-slab ticketed partition (one-time); per-wave exact interval [lo,hi].
//   - exact skip: dist(cx,[lo,hi])^2 >= wm => update is identity (monotone
//     RN: d_p >= fl(dx_p^2) >= fl(dm^2) >= wm >= md_p); cached key exact.
//   - key = (f32bits(max md)<<32) | ~min_orig_idx; u64 max == jnp.argmax
//     first-occurrence.
//   - O(1)-per-wave block reduce: 1 ds_read_b64 (s_wkey[p][lane&15],
//     conflict-free broadcast) + 4-stage DPP u64 butterfly (quad_perm xor1/
//     xor2, row_half_mirror, row_mirror; all lanes valid).
//   - skip test reads wm from REGISTER wkey (lane-63 readlane broadcast).
//   - parity key table + ONE barrier; scalar winner-coord fetch; cluster
//     ids in LDS, bulk store at end.
// Update math: d=((dx*dx)+(dy*dy))+(dz*dz), no FMA (contract off),
// fmin/fmax/select only -> bit-exact vs reference.
// ---------------------------------------------------------------------------
__global__ __launch_bounds__(1024)
__attribute__((amdgpu_waves_per_eu(4, 4)))
void fps_kernel(const float* __restrict__ pos, int* __restrict__ clusters) {
#pragma clang fp contract(off)
    __shared__ unsigned short s_perm[N_PTS];     // 32KB: slot -> original index
    __shared__ int s_cluster[N_CLUSTERS];        // 16KB result accumulator
    __shared__ int s_hist[NBINS];                // histogram -> ticket base
    __shared__ float s_red[32];                  // setup reduce scratch (16 waves x2)
    __shared__ __align__(16) u64 s_wkey[2][16];  // parity-buffered wave keys
    const int t = threadIdx.x;
    const int w = t >> 6, lane = t & 63;
    const int slab = w >> 1, half = w & 1;       // wave pair (2s,2s+1) shares slab s
    const int sbase = slab << 11;                // slab owns slots [2048s,+2048)

    // ---- setup pass 0: global x min/max ----
    float txmin = __builtin_inff(), txmax = -__builtin_inff();
#pragma unroll
    for (int k = 0; k < 16; ++k) {
        const float xv = pos[(t + (k << 10)) * 3];
        txmin = fminf(txmin, xv);
        txmax = fmaxf(txmax, xv);
    }
#pragma unroll
    for (int off = 32; off >= 1; off >>= 1) {
        txmin = fminf(txmin, __shfl_xor(txmin, off));
        txmax = fmaxf(txmax, __shfl_xor(txmax, off));
    }
    if (lane == 0) { s_red[w] = txmin; s_red[16 + w] = txmax; }
    if (t < NBINS) s_hist[t] = 0;
    if (t == 0) s_cluster[0] = 0;
    __syncthreads();
    float gxmin = s_red[0], gxmax = s_red[16];
#pragma unroll
    for (int i = 1; i < 16; ++i) {
        gxmin = fminf(gxmin, s_red[i]);
        gxmax = fmaxf(gxmax, s_red[16 + i]);
    }
    const float binv = (float)NBINS / (gxmax - gxmin);

    // ---- setup pass 1: histogram ----
#pragma unroll
    for (int k = 0; k < 16; ++k) {
        const int i = t + (k << 10);
        int b = (int)((pos[i * 3] - gxmin) * binv);
        b = (b < 0) ? 0 : ((b > NBINS - 1) ? NBINS - 1 : b);
        atomicAdd(&s_hist[b], 1);
    }
    __syncthreads();
    if (t == 0) {   // serial prefix sum (one-time)
        int run = 0;
        for (int b = 0; b < NBINS; ++b) {
            const int c = s_hist[b];
            s_hist[b] = run;
            run += c;
        }
    }
    __syncthreads();
    // ---- setup pass 2: placement (bijective by tickets) ----
#pragma unroll
    for (int k = 0; k < 16; ++k) {
        const int i = t + (k << 10);
        int b = (int)((pos[i * 3] - gxmin) * binv);
        b = (b < 0) ? 0 : ((b > NBINS - 1) ? NBINS - 1 : b);
        const int dest = atomicAdd(&s_hist[b], 1);
        s_perm[dest] = (unsigned short)i;
    }
    __syncthreads();

    // ---- gather coords + packed orig indices + exact wave x-interval ----
    // wave's k-th point lives at slot sbase + 2*k + half (interleave)
    vf2 ax[8], ay[8], az[8], mdv[8];
    unsigned int oid[8];
    float mnx = __builtin_inff(), mxx = -__builtin_inff();
#pragma unroll
    for (int a = 0; a < 8; ++a) {
        const int k0 = (((a << 1) | 0) << 6) + lane;
        const int k1 = (((a << 1) | 1) << 6) + lane;
        const int s0 = sbase + (k0 << 1) + half;
        const int s1 = sbase + (k1 << 1) + half;
        const unsigned int o0 = s_perm[s0], o1 = s_perm[s1];
        oid[a] = (o1 << 16) | o0;
        ax[a] = (vf2){pos[o0 * 3 + 0], pos[o1 * 3 + 0]};
        ay[a] = (vf2){pos[o0 * 3 + 1], pos[o1 * 3 + 1]};
        az[a] = (vf2){pos[o0 * 3 + 2], pos[o1 * 3 + 2]};
        mdv[a] = (vf2){__builtin_inff(), __builtin_inff()};
        mnx = fminf(mnx, fminf(ax[a].x, ax[a].y));
        mxx = fmaxf(mxx, fmaxf(ax[a].x, ax[a].y));
    }
#pragma unroll
    for (int off = 32; off >= 1; off >>= 1) {
        mnx = fminf(mnx, __shfl_xor(mnx, off));
        mxx = fmaxf(mxx, __shfl_xor(mxx, off));
    }
    if (lane == 0) { s_red[w] = mnx; s_red[16 + w] = mxx; }
    __syncthreads();
    const float lo = s_red[w], hi = s_red[16 + w];

    float lx = pos[0], ly = pos[1], lz = pos[2];
    u64 wkey = 0;   // ALL lanes: wave's current key (readlane-broadcast)

// DPP pair-max on (hi_,lo_) u64 key; old=0 masked lanes never win (lo_!=0).
#define PAIR_STAGE(CTRL, RM)                                                          \
    do {                                                                              \
        unsigned int ohi = (unsigned int)__builtin_amdgcn_update_dpp(                 \
            0, (int)hi_, (CTRL), (RM), 0xF, false);                                   \
        unsigned int olo = (unsigned int)__builtin_amdgcn_update_dpp(                 \
            0, (int)lo_, (CTRL), (RM), 0xF, false);                                   \
        u64 cur = ((u64)hi_ << 32) | lo_;                                             \
        u64 oth = ((u64)ohi << 32) | olo;                                             \
        if (oth > cur) { hi_ = ohi; lo_ = olo; }                                      \
    } while (0)

// butterfly stage on u64 e within 16-lane rows (all lanes valid patterns)
#define BFLY_STAGE(CTRL)                                                              \
    do {                                                                              \
        unsigned int ehi = (unsigned int)(e >> 32), elo = (unsigned int)e;            \
        unsigned int ohi = (unsigned int)__builtin_amdgcn_update_dpp(                 \
            0, (int)ehi, (CTRL), 0xF, 0xF, false);                                    \
        unsigned int olo = (unsigned int)__builtin_amdgcn_update_dpp(                 \
            0, (int)elo, (CTRL), 0xF, 0xF, false);                                    \
        const u64 o = ((u64)ohi << 32) | olo;                                         \
        e = (o > e) ? o : e;                                                          \
    } while (0)

// active-wave body: packed update + min-orig-idx recovery + DPP -> wkey,
// then lane-63 readlane broadcast so every lane carries the wave key.
#define UPDATE_AND_KEY()                                                              \
    do {                                                                              \
        const vf2 lxv = (vf2){lx, lx}, lyv = (vf2){ly, ly}, lzv = (vf2){lz, lz};      \
        vf2 bm = (vf2){0.0f, 0.0f};                                                   \
        _Pragma("unroll")                                                             \
        for (int a = 0; a < 8; ++a) {                                                 \
            vf2 dx = ax[a] - lxv;                                                     \
            vf2 dy = ay[a] - lyv;                                                     \
            vf2 dz = az[a] - lzv;                                                     \
            vf2 d = ((dx * dx) + (dy * dy)) + (dz * dz);                              \
            vf2 m;                                                                    \
            m.x = fminf(mdv[a].x, d.x);                                               \
            m.y = fminf(mdv[a].y, d.y);                                               \
            mdv[a] = m;                                                               \
            bm = __builtin_elementwise_max(bm, m);                                    \
        }                                                                             \
        const float bv = fmaxf(bm.x, bm.y);                                           \
        unsigned int mi = 0xffffffffu;                                                \
        _Pragma("unroll")                                                             \
        for (int a = 0; a < 8; ++a) {                                                 \
            const unsigned int c0 =                                                   \
                (mdv[a].x == bv) ? (oid[a] & 0xffffu) : 0xffffffffu;                  \
            const unsigned int c1 =                                                   \
                (mdv[a].y == bv) ? (oid[a] >> 16) : 0xffffffffu;                      \
            const unsigned int cc = (c0 < c1) ? c0 : c1;                              \
            mi = (cc < mi) ? cc : mi;                                                 \
        }                                                                             \
        unsigned int hi_ = __float_as_uint(bv);                                       \
        unsigned int lo_ = ~mi;                                                       \
        PAIR_STAGE(0x111, 0xF);                                                       \
        PAIR_STAGE(0x112, 0xF);                                                       \
        PAIR_STAGE(0x114, 0xF);                                                       \
        PAIR_STAGE(0x118, 0xF);                                                       \
        PAIR_STAGE(0x142, 0xA);                                                       \
        PAIR_STAGE(0x143, 0xC);                                                       \
        hi_ = (unsigned int)__builtin_amdgcn_readlane((int)hi_, 63);                  \
        lo_ = (unsigned int)__builtin_amdgcn_readlane((int)lo_, 63);                  \
        wkey = ((u64)hi_ << 32) | lo_;                                                \
    } while (0)

    // ---- prologue: step-0 update vs cluster 0, publish keys to buf[1] ----
    UPDATE_AND_KEY();
    if (lane == 63) s_wkey[1][w] = wkey;
    __syncthreads();

    for (int step = 1; step < N_CLUSTERS; ++step) {
        const int p = step & 1;
        // ---- O(1)-per-wave block reduce: 1 ds_read_b64 + 4 DPP stages ----
        u64 e = s_wkey[p][lane & 15];
        BFLY_STAGE(0xB1);   // quad_perm [1,0,3,2]  (xor 1)
        BFLY_STAGE(0x4E);   // quad_perm [2,3,0,1]  (xor 2)
        BFLY_STAGE(0x141);  // row_half_mirror      (combines 4 -> 8)
        BFLY_STAGE(0x140);  // row_mirror           (combines 8 -> 16)
        const unsigned int win = ~((unsigned int)e);
        if (t == 0) s_cluster[step] = (int)win;

        // ---- uniform scalar fetch of winner coords ----
        const unsigned int winu =
            (unsigned int)__builtin_amdgcn_readfirstlane((int)win);
        lx = pos[winu * 3 + 0];
        ly = pos[winu * 3 + 1];
        lz = pos[winu * 3 + 2];

        // ---- exact skip test (wm from REGISTER wkey, no LDS read) ----
        const float wm = __uint_as_float((unsigned int)(wkey >> 32));
        const float dm = fmaxf(fmaxf(lo - lx, lx - hi), 0.0f);
        const bool act = (dm * dm < wm);
        if (__builtin_amdgcn_readfirstlane((int)act)) UPDATE_AND_KEY();

        // ---- publish (cached or fresh) key for the NEXT step; one barrier ----
        if (lane == 63) s_wkey[p ^ 1][w] = wkey;
        __syncthreads();
    }
#undef UPDATE_AND_KEY
#undef PAIR_STAGE
#undef BFLY_STAGE

    // bulk coalesced store of the cluster list
    for (int i = t; i < N_CLUSTERS; i += 1024) clusters[i] = s_cluster[i];
}

// ---------------------------------------------------------------------------
// kNN: one block per cluster, 256 threads. d = (qq+pp) - 2*dot (dot FMA-
// ascending like BLAS), LDS distance array per 8192-chunk, 16 argmin rounds
// per chunk (tie -> lower index == stable top_k), exact merge of 2x16.
// Only the neighbor SET matters downstream.
// ---------------------------------------------------------------------------
__global__ __launch_bounds__(256) void knn_kernel(const float* __restrict__ pos,
                                                  const float* __restrict__ pp,
                                                  const int* __restrict__ clusters,
                                                  int* __restrict__ nbr) {
#pragma clang fp contract(off)
    __shared__ float s_d[8192];
    __shared__ float s_rv[4];
    __shared__ int   s_ri[4];
    __shared__ float s_tv[32];
    __shared__ int   s_ti[32];
    const int m = blockIdx.x, t = threadIdx.x;
    const int lane = t & 63, w = t >> 6;

    const int qi = clusters[m];
    const float qx = pos[qi * 3 + 0], qy = pos[qi * 3 + 1], qz = pos[qi * 3 + 2];
    const float qq = ((qx * qx) + (qy * qy)) + (qz * qz);

    for (int chunk = 0; chunk < 2; ++chunk) {
        const int base = chunk << 13;
        __syncthreads();  // protect s_d overwrite vs previous chunk's reads
        for (int i = t; i < 8192; i += 256) {
            const int p = base + i;
            float dot = fmaf(qx, pos[p * 3 + 0], 0.0f);
            dot = fmaf(qy, pos[p * 3 + 1], dot);
            dot = fmaf(qz, pos[p * 3 + 2], dot);
            s_d[i] = (qq + pp[p]) - 2.0f * dot;
        }
        __syncthreads();
        for (int r = 0; r < KNN_K; ++r) {
            float bv = __builtin_inff();
            int   bi = 0x7fffffff;
            for (int i = t; i < 8192; i += 256) {   // i ascending per thread
                float v = s_d[i];
                if (v < bv) { bv = v; bi = i; }     // strict < keeps first
            }
#pragma unroll
            for (int off = 32; off >= 1; off >>= 1) {
                float ov = __shfl_down(bv, off);
                int   oi = __shfl_down(bi, off);
                if (ov < bv || (ov == bv && oi < bi)) { bv = ov; bi = oi; }
            }
            if (lane == 0) { s_rv[w] = bv; s_ri[w] = bi; }
            __syncthreads();
            if (t == 0) {
                float fv = s_rv[0]; int fi = s_ri[0];
#pragma unroll
                for (int ww = 1; ww < 4; ++ww) {
                    if (s_rv[ww] < fv || (s_rv[ww] == fv && s_ri[ww] < fi)) {
                        fv = s_rv[ww]; fi = s_ri[ww];
                    }
                }
                s_tv[chunk * 16 + r] = fv;
                s_ti[chunk * 16 + r] = base + fi;
                s_d[fi] = __builtin_inff();
            }
            __syncthreads();
        }
    }
    if (t == 0) {   // exact merge of two sorted-by-(v,idx) lists
        int a = 0, b = 0;
        for (int r = 0; r < KNN_K; ++r) {
            bool takeA;
            if (b >= 16) takeA = true;
            else if (a >= 16) takeA = false;
            else {
                float va = s_tv[a], vb = s_tv[16 + b];
                takeA = (va < vb) || (va == vb && s_ti[a] < s_ti[16 + b]);
            }
            nbr[m * KNN_K + r] = takeA ? s_ti[a] : s_ti[16 + b];
            if (takeA) ++a; else ++b;
        }
    }
}

// ---------------------------------------------------------------------------
// MLP: grouped[r] = [pos[n]-pos[r>>4] (quirky full-pos indexing!), x[n]],
// h = grouped @ W^T.  PASS 1: accumulate column sum/sumsq.  PASS 2:
// recompute, y = scale*h+shift, out[m,c] = relu(max_k y) (relu∘max=max∘relu),
// plus sub_pos / sub_batch.  64 rows (= 4 whole clusters) x 128 cols / block.
// ---------------------------------------------------------------------------
template <int PASS>
__global__ __launch_bounds__(256) void mlp_kernel(const float* __restrict__ x,
                                                  const float* __restrict__ pos,
                                                  const int* __restrict__ nbr,
                                                  const float* __restrict__ W,
                                                  float* __restrict__ colsum,
                                                  float* __restrict__ colsumsq,
                                                  const float* __restrict__ ss,
                                                  const int* __restrict__ clusters,
                                                  const int* __restrict__ batch,
                                                  float* __restrict__ out) {
    __shared__ __align__(16) float At[FAN_IN][68];     // [i][r], pad 68
    __shared__ __align__(16) float Wl[FAN_IN * 132];   // [i][c], pad 132
    __shared__ float red0[128], red1[128];
    __shared__ float hm[8][132];                       // pass2 half-cluster maxima
    const int tid = threadIdx.x;
    const int R0 = blockIdx.x * 64;

    // stage W transposed
    for (int idx = tid; idx < FAN_IN * 128; idx += 256) {
        int i = idx >> 7, c = idx & 127;
        Wl[i * 132 + c] = W[c * FAN_IN + i];
    }
    // stage A transposed (gather)
    {
        const int wv = tid >> 6, lane = tid & 63;
        for (int r = wv; r < 64; r += 4) {
            const int R = R0 + r;
            const int n = nbr[R];
            At[3 + lane][r] = x[n * C_IN + lane];
            if (lane < 3) {
                const int q = R >> 4;  // faithful to source: cluster ORDINAL indexes pos
                At[lane][r] = pos[n * 3 + lane] - pos[q * 3 + lane];
            }
        }
    }
    if (PASS == 1 && tid < 128) { red0[tid] = 0.0f; red1[tid] = 0.0f; }
    __syncthreads();

    const int g = tid & 31, rg = tid >> 5;
    const int c0 = g * 4, r0 = rg * 8;
    float acc[8][4];
#pragma unroll
    for (int a = 0; a < 8; ++a)
#pragma unroll
        for (int b = 0; b < 4; ++b) acc[a][b] = 0.0f;

    for (int i = 0; i < FAN_IN; ++i) {
        const float4 w4 = *(const float4*)&Wl[i * 132 + c0];
        const float4 a0 = *(const float4*)&At[i][r0];
        const float4 a1 = *(const float4*)&At[i][r0 + 4];
        const float av[8] = {a0.x, a0.y, a0.z, a0.w, a1.x, a1.y, a1.z, a1.w};
        const float wv4[4] = {w4.x, w4.y, w4.z, w4.w};
#pragma unroll
        for (int a = 0; a < 8; ++a)
#pragma unroll
            for (int b = 0; b < 4; ++b) acc[a][b] = fmaf(av[a], wv4[b], acc[a][b]);
    }

    if (PASS == 1) {
#pragma unroll
        for (int b = 0; b < 4; ++b) {
            float s = 0.0f, sq = 0.0f;
#pragma unroll
            for (int a = 0; a < 8; ++a) {
                s += acc[a][b];
                sq = fmaf(acc[a][b], acc[a][b], sq);
            }
            atomicAdd(&red0[c0 + b], s);
            atomicAdd(&red1[c0 + b], sq);
        }
        __syncthreads();
        if (tid < 128) {
            atomicAdd(&colsum[tid], red0[tid]);
            atomicAdd(&colsumsq[tid], red1[tid]);
        }
    } else {
        // rows r0..r0+7 lie in ONE cluster (half of it): reduce then combine
#pragma unroll
        for (int b = 0; b < 4; ++b) {
            const float sc = ss[c0 + b], sh = ss[128 + c0 + b];
            float mx = -__builtin_inff();
#pragma unroll
            for (int a = 0; a < 8; ++a) mx = fmaxf(mx, fmaf(sc, acc[a][b], sh));
            hm[rg][c0 + b] = mx;
        }
        __syncthreads();
        for (int o = tid; o < 512; o += 256) {
            const int cl = o >> 7, c = o & 127;
            const float v = fmaxf(hm[2 * cl][c], hm[2 * cl + 1][c]);
            const int M = blockIdx.x * 4 + cl;
            out[M * 128 + c] = fmaxf(v, 0.0f);
        }
        if (tid < 12) {
            const int cl = tid / 3, l = tid % 3;
            const int M = blockIdx.x * 4 + cl;
            out[524288 + M * 3 + l] = pos[clusters[M] * 3 + l];
        } else if (tid < 16) {
            const int M = blockIdx.x * 4 + (tid - 12);
            out[536576 + M] = (float)batch[clusters[M]];
        }
    }
}

// ---------------------------------------------------------------------------
// stats: scale/shift from column sums (biased var, like torch BN training)
// ---------------------------------------------------------------------------
__global__ void stats_kernel(const float* __restrict__ colsum,
                             const float* __restrict__ colsumsq,
                             const float* __restrict__ gamma,
                             const float* __restrict__ beta,
                             float* __restrict__ ss) {
    const int c = threadIdx.x;
    const float inv_n = 1.0f / (float)N_ROWS;
    const float mean = colsum[c] * inv_n;
    float var = colsumsq[c] * inv_n - mean * mean;
    var = fmaxf(var, 0.0f);
    const float inv = rsqrtf(var + 1e-5f);
    const float sc = gamma[c] * inv;
    ss[c] = sc;
    ss[128 + c] = beta[c] - mean * sc;
}

// ---------------------------------------------------------------------------
extern "C" void kernel_launch(void* const* d_in, const int* in_sizes, int n_in,
                              void* d_out, int out_size, void* d_ws, size_t ws_size,
                              hipStream_t stream) {
    const float* x     = (const float*)d_in[0];
    const float* pos   = (const float*)d_in[1];
    const int*   batch = (const int*)d_in[2];
    const float* W     = (const float*)d_in[3];
    const float* gamma = (const float*)d_in[4];
    const float* beta  = (const float*)d_in[5];
    float* out = (float*)d_out;
    float* wsf = (float*)d_ws;

    int*   clusters = (int*)d_ws;            // [4096]
    int*   nbr      = clusters + 4096;       // [65536]
    float* pp       = wsf + 69632;           // [16384]
    float* colsum   = wsf + 86016;           // [128]
    float* colsumsq = wsf + 86144;           // [128]
    float* ss       = wsf + 86272;           // [256]

    init_kernel<<<dim3(64), dim3(256), 0, stream>>>(pos, pp, colsum);
    fps_kernel<<<dim3(1), dim3(1024), 0, stream>>>(pos, clusters);
    knn_kernel<<<dim3(N_CLUSTERS), dim3(256), 0, stream>>>(pos, pp, clusters, nbr);
    mlp_kernel<1><<<dim3(1024), dim3(256), 0, stream>>>(x, pos, nbr, W, colsum, colsumsq,
                                                        ss, clusters, batch, out);
    stats_kernel<<<dim3(1), dim3(128), 0, stream>>>(colsum, colsumsq, gamma, beta, ss);
    mlp_kernel<2><<<dim3(1024), dim3(256), 0, stream>>>(x, pos, nbr, W, colsum, colsumsq,
                                                        ss, clusters, batch, out);
}

// Round 16
// 4139.090 us; speedup vs baseline: 1.0390x; 1.0390x over previous
//
#include <hip/hip_runtime.h>
#include <math.h>

#define N_PTS 16384
#define N_CLUSTERS 4096
#define KNN_K 16
#define C_IN 64
#define C_OUT 128
#define FAN_IN 67
#define N_ROWS (N_CLUSTERS * KNN_K)   // 65536
#define NBINS 256

typedef float vf2 __attribute__((ext_vector_type(2)));
typedef unsigned long long u64;

// ---------------------------------------------------------------------------
// init: pp[i] = |pos_i|^2 (reference op order, no FMA), zero colsum/colsumsq
// ---------------------------------------------------------------------------
__global__ void init_kernel(const float* __restrict__ pos, float* __restrict__ pp,
                            float* __restrict__ cz) {
#pragma clang fp contract(off)
    int i = blockIdx.x * 256 + threadIdx.x;
    if (i < N_PTS) {
        float a = pos[i * 3 + 0], b = pos[i * 3 + 1], c = pos[i * 3 + 2];
        pp[i] = ((a * a) + (b * b)) + (c * c);
    }
    if (blockIdx.x == 0 && threadIdx.x < 256) cz[threadIdx.x] = 0.0f;
}

// ---------------------------------------------------------------------------
// FPS v19 = v17 RESTORED VERBATIM (session best: fps 3625us, total 4161us).
// Final structure after 15 rounds of systematic search:
//   - 1024 threads / 16 waves (4/SIMD), 16 pts/thread as 8 vf2 pairs.
//   - x-slab ticketed partition (256-bin histogram, one-time); wave w owns
//     slots [1024w,+1024) = contiguous x-slab with exact interval [lo,hi].
//   - exact skip: dist(cx,[lo,hi])^2 >= wm => whole-wave update is identity
//     (monotone RN rounding: d_p >= fl(dx_p^2) >= fl(dm^2) >= wm >= md_p);
//     skipped wave's cached key stays exact.  [v9/v10]
//   - key = (f32bits(max md)<<32) | ~min_orig_idx; u64 max == (max value,
//     tie -> min ORIGINAL index) == jnp.argmax first-occurrence;
//     placement-invariant.  [v10]
//   - single-barrier parity keyed reduce (s_wkey[(step+1)&1][w]).  [v10]
//   - O(1)-per-wave block reduce: 1 ds_read_b64 (s_wkey[p][lane&15],
//     conflict-free broadcast) + 4-stage DPP u64 butterfly.  [v17]
//   - skip test reads wm from REGISTER wkey (lane-63 readlane broadcast).
//   - winner coords via readfirstlane + scalar load; cluster ids in LDS,
//     bulk coalesced store at the end.
// Refuted alternatives (measured): packed-asm ops (v7), multi-CU mailbox
// (v8, cross-XCD sync >=1500cyc), octants (v11, corner-at-mean), intra-wave
// branches (v12), AGPR fence (v14, over-budget), slab-pair interleave (v18,
// +1 boundary term).  Remaining step budget (~2125cyc) is a serial
// dependency floor: update issue + butterfly + coord fetch + barrier, all
// load-bearing.
// Update math: d=((dx*dx)+(dy*dy))+(dz*dz), no FMA (contract off),
// fmin/fmax/select only -> bit-exact winner sequence vs reference.
// ---------------------------------------------------------------------------
__global__ __launch_bounds__(1024)
__attribute__((amdgpu_waves_per_eu(4, 4)))
void fps_kernel(const float* __restrict__ pos, int* __restrict__ clusters) {
#pragma clang fp contract(off)
    __shared__ unsigned short s_perm[N_PTS];     // 32KB: slot -> original index
    __shared__ int s_cluster[N_CLUSTERS];        // 16KB result accumulator
    __shared__ int s_hist[NBINS];                // histogram -> ticket base
    __shared__ float s_red[32];                  // setup reduce scratch (16 waves x2)
    __shared__ __align__(16) u64 s_wkey[2][16];  // parity-buffered wave keys
    const int t = threadIdx.x;
    const int w = t >> 6, lane = t & 63;
    const int wbase = w << 10;                   // wave owns slots [w*1024,+1024)

    // ---- setup pass 0: global x min/max ----
    float txmin = __builtin_inff(), txmax = -__builtin_inff();
#pragma unroll
    for (int k = 0; k < 16; ++k) {
        const float xv = pos[(t + (k << 10)) * 3];
        txmin = fminf(txmin, xv);
        txmax = fmaxf(txmax, xv);
    }
#pragma unroll
    for (int off = 32; off >= 1; off >>= 1) {
        txmin = fminf(txmin, __shfl_xor(txmin, off));
        txmax = fmaxf(txmax, __shfl_xor(txmax, off));
    }
    if (lane == 0) { s_red[w] = txmin; s_red[16 + w] = txmax; }
    if (t < NBINS) s_hist[t] = 0;
    if (t == 0) s_cluster[0] = 0;
    __syncthreads();
    float gxmin = s_red[0], gxmax = s_red[16];
#pragma unroll
    for (int i = 1; i < 16; ++i) {
        gxmin = fminf(gxmin, s_red[i]);
        gxmax = fmaxf(gxmax, s_red[16 + i]);
    }
    const float binv = (float)NBINS / (gxmax - gxmin);

    // ---- setup pass 1: histogram ----
#pragma unroll
    for (int k = 0; k < 16; ++k) {
        const int i = t + (k << 10);
        int b = (int)((pos[i * 3] - gxmin) * binv);
        b = (b < 0) ? 0 : ((b > NBINS - 1) ? NBINS - 1 : b);
        atomicAdd(&s_hist[b], 1);
    }
    __syncthreads();
    if (t == 0) {   // serial prefix sum (one-time)
        int run = 0;
        for (int b = 0; b < NBINS; ++b) {
            const int c = s_hist[b];
            s_hist[b] = run;
            run += c;
        }
    }
    __syncthreads();
    // ---- setup pass 2: placement (bijective by tickets) ----
#pragma unroll
    for (int k = 0; k < 16; ++k) {
        const int i = t + (k << 10);
        int b = (int)((pos[i * 3] - gxmin) * binv);
        b = (b < 0) ? 0 : ((b > NBINS - 1) ? NBINS - 1 : b);
        const int dest = atomicAdd(&s_hist[b], 1);
        s_perm[dest] = (unsigned short)i;
    }
    __syncthreads();

    // ---- gather coords + packed original indices + exact wave x-interval ----
    vf2 ax[8], ay[8], az[8], mdv[8];
    unsigned int oid[8];
    float mnx = __builtin_inff(), mxx = -__builtin_inff();
#pragma unroll
    for (int a = 0; a < 8; ++a) {
        const int s0 = wbase + (((a << 1) | 0) << 6) + lane;
        const int s1 = wbase + (((a << 1) | 1) << 6) + lane;
        const unsigned int o0 = s_perm[s0], o1 = s_perm[s1];
        oid[a] = (o1 << 16) | o0;
        ax[a] = (vf2){pos[o0 * 3 + 0], pos[o1 * 3 + 0]};
        ay[a] = (vf2){pos[o0 * 3 + 1], pos[o1 * 3 + 1]};
        az[a] = (vf2){pos[o0 * 3 + 2], pos[o1 * 3 + 2]};
        mdv[a] = (vf2){__builtin_inff(), __builtin_inff()};
        mnx = fminf(mnx, fminf(ax[a].x, ax[a].y));
        mxx = fmaxf(mxx, fmaxf(ax[a].x, ax[a].y));
    }
#pragma unroll
    for (int off = 32; off >= 1; off >>= 1) {
        mnx = fminf(mnx, __shfl_xor(mnx, off));
        mxx = fmaxf(mxx, __shfl_xor(mxx, off));
    }
    if (lane == 0) { s_red[w] = mnx; s_red[16 + w] = mxx; }
    __syncthreads();
    const float lo = s_red[w], hi = s_red[16 + w];

    float lx = pos[0], ly = pos[1], lz = pos[2];
    u64 wkey = 0;   // ALL lanes: wave's current key (readlane-broadcast)

// DPP pair-max on (hi_,lo_) u64 key; old=0 masked lanes never win (lo_!=0).
#define PAIR_STAGE(CTRL, RM)                                                          \
    do {                                                                              \
        unsigned int ohi = (unsigned int)__builtin_amdgcn_update_dpp(                 \
            0, (int)hi_, (CTRL), (RM), 0xF, false);                                   \
        unsigned int olo = (unsigned int)__builtin_amdgcn_update_dpp(                 \
            0, (int)lo_, (CTRL), (RM), 0xF, false);                                   \
        u64 cur = ((u64)hi_ << 32) | lo_;                                             \
        u64 oth = ((u64)ohi << 32) | olo;                                             \
        if (oth > cur) { hi_ = ohi; lo_ = olo; }                                      \
    } while (0)

// butterfly stage on u64 e within 16-lane rows (all lanes valid patterns)
#define BFLY_STAGE(CTRL)                                                              \
    do {                                                                              \
        unsigned int ehi = (unsigned int)(e >> 32), elo = (unsigned int)e;            \
        unsigned int ohi = (unsigned int)__builtin_amdgcn_update_dpp(                 \
            0, (int)ehi, (CTRL), 0xF, 0xF, false);                                    \
        unsigned int olo = (unsigned int)__builtin_amdgcn_update_dpp(                 \
            0, (int)elo, (CTRL), 0xF, 0xF, false);                                    \
        const u64 o = ((u64)ohi << 32) | olo;                                         \
        e = (o > e) ? o : e;                                                          \
    } while (0)

// active-wave body: packed update + min-orig-idx recovery + DPP -> wkey,
// then lane-63 readlane broadcast so every lane carries the wave key.
#define UPDATE_AND_KEY()                                                              \
    do {                                                                              \
        const vf2 lxv = (vf2){lx, lx}, lyv = (vf2){ly, ly}, lzv = (vf2){lz, lz};      \
        vf2 bm = (vf2){0.0f, 0.0f};                                                   \
        _Pragma("unroll")                                                             \
        for (int a = 0; a < 8; ++a) {                                                 \
            vf2 dx = ax[a] - lxv;                                                     \
            vf2 dy = ay[a] - lyv;                                                     \
            vf2 dz = az[a] - lzv;                                                     \
            vf2 d = ((dx * dx) + (dy * dy)) + (dz * dz);                              \
            vf2 m;                                                                    \
            m.x = fminf(mdv[a].x, d.x);                                               \
            m.y = fminf(mdv[a].y, d.y);                                               \
            mdv[a] = m;                                                               \
            bm = __builtin_elementwise_max(bm, m);                                    \
        }                                                                             \
        const float bv = fmaxf(bm.x, bm.y);                                           \
        unsigned int mi = 0xffffffffu;                                                \
        _Pragma("unroll")                                                             \
        for (int a = 0; a < 8; ++a) {                                                 \
            const unsigned int c0 =                                                   \
                (mdv[a].x == bv) ? (oid[a] & 0xffffu) : 0xffffffffu;                  \
            const unsigned int c1 =                                                   \
                (mdv[a].y == bv) ? (oid[a] >> 16) : 0xffffffffu;                      \
            const unsigned int cc = (c0 < c1) ? c0 : c1;                              \
            mi = (cc < mi) ? cc : mi;                                                 \
        }                                                                             \
        unsigned int hi_ = __float_as_uint(bv);                                       \
        unsigned int lo_ = ~mi;                                                       \
        PAIR_STAGE(0x111, 0xF);                                                       \
        PAIR_STAGE(0x112, 0xF);                                                       \
        PAIR_STAGE(0x114, 0xF);                                                       \
        PAIR_STAGE(0x118, 0xF);                                                       \
        PAIR_STAGE(0x142, 0xA);                                                       \
        PAIR_STAGE(0x143, 0xC);                                                       \
        hi_ = (unsigned int)__builtin_amdgcn_readlane((int)hi_, 63);                  \
        lo_ = (unsigned int)__builtin_amdgcn_readlane((int)lo_, 63);                  \
        wkey = ((u64)hi_ << 32) | lo_;                                                \
    } while (0)

    // ---- prologue: step-0 update vs cluster 0, publish keys to buf[1] ----
    UPDATE_AND_KEY();
    if (lane == 63) s_wkey[1][w] = wkey;
    __syncthreads();

    for (int step = 1; step < N_CLUSTERS; ++step) {
        const int p = step & 1;
        // ---- O(1)-per-wave block reduce: 1 ds_read_b64 + 4 DPP stages ----
        u64 e = s_wkey[p][lane & 15];
        BFLY_STAGE(0xB1);   // quad_perm [1,0,3,2]  (xor 1)
        BFLY_STAGE(0x4E);   // quad_perm [2,3,0,1]  (xor 2)
        BFLY_STAGE(0x141);  // row_half_mirror      (combines 4 -> 8)
        BFLY_STAGE(0x140);  // row_mirror           (combines 8 -> 16)
        const unsigned int win = ~((unsigned int)e);
        if (t == 0) s_cluster[step] = (int)win;

        // ---- uniform scalar fetch of winner coords ----
        const unsigned int winu =
            (unsigned int)__builtin_amdgcn_readfirstlane((int)win);
        lx = pos[winu * 3 + 0];
        ly = pos[winu * 3 + 1];
        lz = pos[winu * 3 + 2];

        // ---- exact skip test (wm from REGISTER wkey, no LDS read) ----
        const float wm = __uint_as_float((unsigned int)(wkey >> 32));
        const float dm = fmaxf(fmaxf(lo - lx, lx - hi), 0.0f);
        const bool act = (dm * dm < wm);
        if (__builtin_amdgcn_readfirstlane((int)act)) UPDATE_AND_KEY();

        // ---- publish (cached or fresh) key for the NEXT step; one barrier ----
        if (lane == 63) s_wkey[p ^ 1][w] = wkey;
        __syncthreads();
    }
#undef UPDATE_AND_KEY
#undef PAIR_STAGE
#undef BFLY_STAGE

    // bulk coalesced store of the cluster list
    for (int i = t; i < N_CLUSTERS; i += 1024) clusters[i] = s_cluster[i];
}

// ---------------------------------------------------------------------------
// kNN: one block per cluster, 256 threads. d = (qq+pp) - 2*dot (dot FMA-
// ascending like BLAS), LDS distance array per 8192-chunk, 16 argmin rounds
// per chunk (tie -> lower index == stable top_k), exact merge of 2x16.
// Only the neighbor SET matters downstream.
// ---------------------------------------------------------------------------
__global__ __launch_bounds__(256) void knn_kernel(const float* __restrict__ pos,
                                                  const float* __restrict__ pp,
                                                  const int* __restrict__ clusters,
                                                  int* __restrict__ nbr) {
#pragma clang fp contract(off)
    __shared__ float s_d[8192];
    __shared__ float s_rv[4];
    __shared__ int   s_ri[4];
    __shared__ float s_tv[32];
    __shared__ int   s_ti[32];
    const int m = blockIdx.x, t = threadIdx.x;
    const int lane = t & 63, w = t >> 6;

    const int qi = clusters[m];
    const float qx = pos[qi * 3 + 0], qy = pos[qi * 3 + 1], qz = pos[qi * 3 + 2];
    const float qq = ((qx * qx) + (qy * qy)) + (qz * qz);

    for (int chunk = 0; chunk < 2; ++chunk) {
        const int base = chunk << 13;
        __syncthreads();  // protect s_d overwrite vs previous chunk's reads
        for (int i = t; i < 8192; i += 256) {
            const int p = base + i;
            float dot = fmaf(qx, pos[p * 3 + 0], 0.0f);
            dot = fmaf(qy, pos[p * 3 + 1], dot);
            dot = fmaf(qz, pos[p * 3 + 2], dot);
            s_d[i] = (qq + pp[p]) - 2.0f * dot;
        }
        __syncthreads();
        for (int r = 0; r < KNN_K; ++r) {
            float bv = __builtin_inff();
            int   bi = 0x7fffffff;
            for (int i = t; i < 8192; i += 256) {   // i ascending per thread
                float v = s_d[i];
                if (v < bv) { bv = v; bi = i; }     // strict < keeps first
            }
#pragma unroll
            for (int off = 32; off >= 1; off >>= 1) {
                float ov = __shfl_down(bv, off);
                int   oi = __shfl_down(bi, off);
                if (ov < bv || (ov == bv && oi < bi)) { bv = ov; bi = oi; }
            }
            if (lane == 0) { s_rv[w] = bv; s_ri[w] = bi; }
            __syncthreads();
            if (t == 0) {
                float fv = s_rv[0]; int fi = s_ri[0];
#pragma unroll
                for (int ww = 1; ww < 4; ++ww) {
                    if (s_rv[ww] < fv || (s_rv[ww] == fv && s_ri[ww] < fi)) {
                        fv = s_rv[ww]; fi = s_ri[ww];
                    }
                }
                s_tv[chunk * 16 + r] = fv;
                s_ti[chunk * 16 + r] = base + fi;
                s_d[fi] = __builtin_inff();
            }
            __syncthreads();
        }
    }
    if (t == 0) {   // exact merge of two sorted-by-(v,idx) lists
        int a = 0, b = 0;
        for (int r = 0; r < KNN_K; ++r) {
            bool takeA;
            if (b >= 16) takeA = true;
            else if (a >= 16) takeA = false;
            else {
                float va = s_tv[a], vb = s_tv[16 + b];
                takeA = (va < vb) || (va == vb && s_ti[a] < s_ti[16 + b]);
            }
            nbr[m * KNN_K + r] = takeA ? s_ti[a] : s_ti[16 + b];
            if (takeA) ++a; else ++b;
        }
    }
}

// ---------------------------------------------------------------------------
// MLP: grouped[r] = [pos[n]-pos[r>>4] (quirky full-pos indexing!), x[n]],
// h = grouped @ W^T.  PASS 1: accumulate column sum/sumsq.  PASS 2:
// recompute, y = scale*h+shift, out[m,c] = relu(max_k y) (relu∘max=max∘relu),
// plus sub_pos / sub_batch.  64 rows (= 4 whole clusters) x 128 cols / block.
// ---------------------------------------------------------------------------
template <int PASS>
__global__ __launch_bounds__(256) void mlp_kernel(const float* __restrict__ x,
                                                  const float* __restrict__ pos,
                                                  const int* __restrict__ nbr,
                                                  const float* __restrict__ W,
                                                  float* __restrict__ colsum,
                                                  float* __restrict__ colsumsq,
                                                  const float* __restrict__ ss,
                                                  const int* __restrict__ clusters,
                                                  const int* __restrict__ batch,
                                                  float* __restrict__ out) {
    __shared__ __align__(16) float At[FAN_IN][68];     // [i][r], pad 68
    __shared__ __align__(16) float Wl[FAN_IN * 132];   // [i][c], pad 132
    __shared__ float red0[128], red1[128];
    __shared__ float hm[8][132];                       // pass2 half-cluster maxima
    const int tid = threadIdx.x;
    const int R0 = blockIdx.x * 64;

    // stage W transposed
    for (int idx = tid; idx < FAN_IN * 128; idx += 256) {
        int i = idx >> 7, c = idx & 127;
        Wl[i * 132 + c] = W[c * FAN_IN + i];
    }
    // stage A transposed (gather)
    {
        const int wv = tid >> 6, lane = tid & 63;
        for (int r = wv; r < 64; r += 4) {
            const int R = R0 + r;
            const int n = nbr[R];
            At[3 + lane][r] = x[n * C_IN + lane];
            if (lane < 3) {
                const int q = R >> 4;  // faithful to source: cluster ORDINAL indexes pos
                At[lane][r] = pos[n * 3 + lane] - pos[q * 3 + lane];
            }
        }
    }
    if (PASS == 1 && tid < 128) { red0[tid] = 0.0f; red1[tid] = 0.0f; }
    __syncthreads();

    const int g = tid & 31, rg = tid >> 5;
    const int c0 = g * 4, r0 = rg * 8;
    float acc[8][4];
#pragma unroll
    for (int a = 0; a < 8; ++a)
#pragma unroll
        for (int b = 0; b < 4; ++b) acc[a][b] = 0.0f;

    for (int i = 0; i < FAN_IN; ++i) {
        const float4 w4 = *(const float4*)&Wl[i * 132 + c0];
        const float4 a0 = *(const float4*)&At[i][r0];
        const float4 a1 = *(const float4*)&At[i][r0 + 4];
        const float av[8] = {a0.x, a0.y, a0.z, a0.w, a1.x, a1.y, a1.z, a1.w};
        const float wv4[4] = {w4.x, w4.y, w4.z, w4.w};
#pragma unroll
        for (int a = 0; a < 8; ++a)
#pragma unroll
            for (int b = 0; b < 4; ++b) acc[a][b] = fmaf(av[a], wv4[b], acc[a][b]);
    }

    if (PASS == 1) {
#pragma unroll
        for (int b = 0; b < 4; ++b) {
            float s = 0.0f, sq = 0.0f;
#pragma unroll
            for (int a = 0; a < 8; ++a) {
                s += acc[a][b];
                sq = fmaf(acc[a][b], acc[a][b], sq);
            }
            atomicAdd(&red0[c0 + b], s);
            atomicAdd(&red1[c0 + b], sq);
        }
        __syncthreads();
        if (tid < 128) {
            atomicAdd(&colsum[tid], red0[tid]);
            atomicAdd(&colsumsq[tid], red1[tid]);
        }
    } else {
        // rows r0..r0+7 lie in ONE cluster (half of it): reduce then combine
#pragma unroll
        for (int b = 0; b < 4; ++b) {
            const float sc = ss[c0 + b], sh = ss[128 + c0 + b];
            float mx = -__builtin_inff();
#pragma unroll
            for (int a = 0; a < 8; ++a) mx = fmaxf(mx, fmaf(sc, acc[a][b], sh));
            hm[rg][c0 + b] = mx;
        }
        __syncthreads();
        for (int o = tid; o < 512; o += 256) {
            const int cl = o >> 7, c = o & 127;
            const float v = fmaxf(hm[2 * cl][c], hm[2 * cl + 1][c]);
            const int M = blockIdx.x * 4 + cl;
            out[M * 128 + c] = fmaxf(v, 0.0f);
        }
        if (tid < 12) {
            const int cl = tid / 3, l = tid % 3;
            const int M = blockIdx.x * 4 + cl;
            out[524288 + M * 3 + l] = pos[clusters[M] * 3 + l];
        } else if (tid < 16) {
            const int M = blockIdx.x * 4 + (tid - 12);
            out[536576 + M] = (float)batch[clusters[M]];
        }
    }
}

// ---------------------------------------------------------------------------
// stats: scale/shift from column sums (biased var, like torch BN training)
// ---------------------------------------------------------------------------
__global__ void stats_kernel(const float* __restrict__ colsum,
                             const float* __restrict__ colsumsq,
                             const float* __restrict__ gamma,
                             const float* __restrict__ beta,
                             float* __restrict__ ss) {
    const int c = threadIdx.x;
    const float inv_n = 1.0f / (float)N_ROWS;
    const float mean = colsum[c] * inv_n;
    float var = colsumsq[c] * inv_n - mean * mean;
    var = fmaxf(var, 0.0f);
    const float inv = rsqrtf(var + 1e-5f);
    const float sc = gamma[c] * inv;
    ss[c] = sc;
    ss[128 + c] = beta[c] - mean * sc;
}

// ---------------------------------------------------------------------------
extern "C" void kernel_launch(void* const* d_in, const int* in_sizes, int n_in,
                              void* d_out, int out_size, void* d_ws, size_t ws_size,
                              hipStream_t stream) {
    const float* x     = (const float*)d_in[0];
    const float* pos   = (const float*)d_in[1];
    const int*   batch = (const int*)d_in[2];
    const float* W     = (const float*)d_in[3];
    const float* gamma = (const float*)d_in[4];
    const float* beta  = (const float*)d_in[5];
    float* out = (float*)d_out;
    float* wsf = (float*)d_ws;

    int*   clusters = (int*)d_ws;            // [4096]
    int*   nbr      = clusters + 4096;       // [65536]
    float* pp       = wsf + 69632;           // [16384]
    float* colsum   = wsf + 86016;           // [128]
    float* colsumsq = wsf + 86144;           // [128]
    float* ss       = wsf + 86272;           // [256]

    init_kernel<<<dim3(64), dim3(256), 0, stream>>>(pos, pp, colsum);
    fps_kernel<<<dim3(1), dim3(1024), 0, stream>>>(pos, clusters);
    knn_kernel<<<dim3(N_CLUSTERS), dim3(256), 0, stream>>>(pos, pp, clusters, nbr);
    mlp_kernel<1><<<dim3(1024), dim3(256), 0, stream>>>(x, pos, nbr, W, colsum, colsumsq,
                                                        ss, clusters, batch, out);
    stats_kernel<<<dim3(1), dim3(128), 0, stream>>>(colsum, colsumsq, gamma, beta, ss);
    mlp_kernel<2><<<dim3(1024), dim3(256), 0, stream>>>(x, pos, nbr, W, colsum, colsumsq,
                                                        ss, clusters, batch, out);
}